// Round 4
// baseline (88.151 us; speedup 1.0000x reference)
//
#include <hip/hip_runtime.h>
#include <math.h>

#define N_ANCH 10647
#define N_GT   2048
#define N_OUTC 85
#define PRED_ELEMS (N_ANCH * N_OUTC)   // 904995
#define PRED_V4    (PRED_ELEMS / 4)    // 226248 (3 tail floats)
#define N_CHUNK    42                  // ceil(10647/256)
#define NBLK_IOU   672                 // 336 anchor-side + 336 gt-side
#define CPY_PER_BLK 337                // ceil(PRED_V4 / NBLK_IOU)

struct WS {
    unsigned long long akey[N_ANCH];   // packed (iou_bits<<32)|~gt_idx   (memset 0)
    unsigned long long gkey[N_GT];     // packed (iou_bits<<32)|~anchor_idx (memset 0)
    int lab[N_ANCH];                   // -1/0/1 labels (pre-demote)
    int cnt_p[N_CHUNK], cnt_n[N_CHUNK];
    float acc[3];                      // box+obj, cls, neg  (memset 0)
    unsigned int done;                 // last-block counter (memset 0)
};

__device__ __forceinline__ float bce(float x, float t) {
    // matches: max(x,0) - x*t + log1p(exp(-|x|))
    return fmaxf(x, 0.0f) - x * t + log1pf(expf(-fabsf(x)));
}

__device__ __forceinline__ unsigned long long packkey(float iou, int idx) {
    return ((unsigned long long)__float_as_uint(iou) << 32) |
           (unsigned)(~(unsigned)idx);
}

// ---------------- K1: pred->out copy + fused IoU reductions ----------------
// blocks [0,336):   anchor side. bx=b%21 (512 anchors, 2/thread), by=b/21 (16 x 128 GTs)
// blocks [336,672): gt side.     bx=b2%4 (512 GTs, 2/thread),     by=b2/4 (84 x 128 anchors)
__global__ __launch_bounds__(256) void k_iou(const float* __restrict__ pred,
                                             const float* __restrict__ gtb,
                                             const float* __restrict__ priors,
                                             float* __restrict__ out,
                                             WS* __restrict__ ws) {
    int b = blockIdx.x, t = threadIdx.x;
    // distributed pred -> out copy (overlaps with compute below)
    for (int k = t; k < CPY_PER_BLK; k += 256) {
        int idx = b * CPY_PER_BLK + k;
        if (idx < PRED_V4)
            ((float4*)out)[idx] = ((const float4*)pred)[idx];
    }
    if (b == 0 && t == 0) {
        out[PRED_ELEMS - 3] = pred[PRED_ELEMS - 3];
        out[PRED_ELEMS - 2] = pred[PRED_ELEMS - 2];
        out[PRED_ELEMS - 1] = pred[PRED_ELEMS - 1];
    }

    __shared__ float4 sc[128];
    __shared__ float  sa[128];

    if (b < 336) {
        // ---- anchor side ----
        int bx = b % 21, by = b / 21;
        int jbase = by * 128;
        if (t < 128) {
            float4 v = ((const float4*)gtb)[jbase + t];
            float4 c = make_float4(v.x - v.z*0.5f, v.y - v.w*0.5f,
                                   v.x + v.z*0.5f, v.y + v.w*0.5f);
            sc[t] = c;
            sa[t] = (c.z - c.x) * (c.w - c.y);
        }
        int i0 = bx * 512 + t, i1 = i0 + 256;
        bool v0 = (i0 < N_ANCH), v1 = (i1 < N_ANCH);
        float4 a0 = make_float4(0.f,0.f,0.f,0.f), a1 = a0;
        float aa0 = 0.f, aa1 = 0.f;
        if (v0) {
            float cx = priors[i0*N_OUTC+0], cy = priors[i0*N_OUTC+1];
            float w  = priors[i0*N_OUTC+2], h  = priors[i0*N_OUTC+3];
            a0 = make_float4(cx - w*0.5f, cy - h*0.5f, cx + w*0.5f, cy + h*0.5f);
            aa0 = (a0.z - a0.x) * (a0.w - a0.y);
        }
        if (v1) {
            float cx = priors[i1*N_OUTC+0], cy = priors[i1*N_OUTC+1];
            float w  = priors[i1*N_OUTC+2], h  = priors[i1*N_OUTC+3];
            a1 = make_float4(cx - w*0.5f, cy - h*0.5f, cx + w*0.5f, cy + h*0.5f);
            aa1 = (a1.z - a1.x) * (a1.w - a1.y);
        }
        __syncthreads();
        float bi0 = -1.0f, bi1 = -1.0f;
        int bj0 = 0, bj1 = 0;
#pragma unroll 4
        for (int jj = 0; jj < 128; ++jj) {
            float4 g = sc[jj]; float ga = sa[jj];
            float lx0 = fmaxf(a0.x, g.x), ly0 = fmaxf(a0.y, g.y);
            float rx0 = fminf(a0.z, g.z), ry0 = fminf(a0.w, g.w);
            float w0 = fmaxf(rx0 - lx0, 0.f), h0 = fmaxf(ry0 - ly0, 0.f);
            float in0 = w0 * h0;
            float iou0 = in0 / ((aa0 + ga) - in0);
            float lx1 = fmaxf(a1.x, g.x), ly1 = fmaxf(a1.y, g.y);
            float rx1 = fminf(a1.z, g.z), ry1 = fminf(a1.w, g.w);
            float w1 = fmaxf(rx1 - lx1, 0.f), h1 = fmaxf(ry1 - ly1, 0.f);
            float in1 = w1 * h1;
            float iou1 = in1 / ((aa1 + ga) - in1);
            bool g0 = iou0 > bi0;            // strict > : first index on ties
            bi0 = g0 ? iou0 : bi0; bj0 = g0 ? jj : bj0;
            bool g1 = iou1 > bi1;
            bi1 = g1 ? iou1 : bi1; bj1 = g1 ? jj : bj1;
        }
        if (v0) atomicMax(&ws->akey[i0], packkey(bi0, jbase + bj0));
        if (v1) atomicMax(&ws->akey[i1], packkey(bi1, jbase + bj1));
    } else {
        // ---- gt side ----
        int b2 = b - 336;
        int bx = b2 % 4, by = b2 / 4;
        int ibase = by * 128;
        if (t < 128) {
            int i = ibase + t;
            float4 c = make_float4(0.f,0.f,0.f,0.f);
            float ar = 0.f;
            if (i < N_ANCH) {
                float cx = priors[i*N_OUTC+0], cy = priors[i*N_OUTC+1];
                float w  = priors[i*N_OUTC+2], h  = priors[i*N_OUTC+3];
                c = make_float4(cx - w*0.5f, cy - h*0.5f, cx + w*0.5f, cy + h*0.5f);
                ar = (c.z - c.x) * (c.w - c.y);
            }
            // pads: iou = 0 at chunk-tail indices; strict > never picks them
            // over an earlier real anchor with iou >= 0.
            sc[t] = c; sa[t] = ar;
        }
        int j0 = bx * 512 + t, j1 = j0 + 256;
        float4 v = ((const float4*)gtb)[j0];
        float4 g0 = make_float4(v.x - v.z*0.5f, v.y - v.w*0.5f,
                                v.x + v.z*0.5f, v.y + v.w*0.5f);
        float ga0 = (g0.z - g0.x) * (g0.w - g0.y);
        v = ((const float4*)gtb)[j1];
        float4 g1 = make_float4(v.x - v.z*0.5f, v.y - v.w*0.5f,
                                v.x + v.z*0.5f, v.y + v.w*0.5f);
        float ga1 = (g1.z - g1.x) * (g1.w - g1.y);
        __syncthreads();
        float bi0 = -1.0f, bi1 = -1.0f;
        int bii0 = 0, bii1 = 0;
#pragma unroll 4
        for (int ii = 0; ii < 128; ++ii) {
            float4 a = sc[ii]; float aa = sa[ii];
            float lx0 = fmaxf(a.x, g0.x), ly0 = fmaxf(a.y, g0.y);
            float rx0 = fminf(a.z, g0.z), ry0 = fminf(a.w, g0.w);
            float w0 = fmaxf(rx0 - lx0, 0.f), h0 = fmaxf(ry0 - ly0, 0.f);
            float in0 = w0 * h0;
            float iou0 = in0 / ((aa + ga0) - in0);
            float lx1 = fmaxf(a.x, g1.x), ly1 = fmaxf(a.y, g1.y);
            float rx1 = fminf(a.z, g1.z), ry1 = fminf(a.w, g1.w);
            float w1 = fmaxf(rx1 - lx1, 0.f), h1 = fmaxf(ry1 - ly1, 0.f);
            float in1 = w1 * h1;
            float iou1 = in1 / ((aa + ga1) - in1);
            bool c0 = iou0 > bi0;
            bi0 = c0 ? iou0 : bi0; bii0 = c0 ? ii : bii0;
            bool c1 = iou1 > bi1;
            bi1 = c1 ? iou1 : bi1; bii1 = c1 ? ii : bii1;
        }
        atomicMax(&ws->gkey[j0], packkey(bi0, ibase + bii0));
        atomicMax(&ws->gkey[j1], packkey(bi1, ibase + bii1));
    }
}

// ---------------- K2: per-chunk labels + counts (parallel) ----------------
__global__ __launch_bounds__(256) void k_label(WS* __restrict__ ws) {
    __shared__ int flg[256];
    __shared__ int wp[4], wn[4];
    int b = blockIdx.x, t = threadIdx.x, base = b * 256;
    int lane = t & 63, wid = t >> 6;
    flg[t] = 0;
    __syncthreads();
    for (int j = t; j < N_GT; j += 256) {
        int ai = (int)(~(unsigned)(ws->gkey[j]));
        int rel = ai - base;
        if ((unsigned)rel < 256u) flg[rel] = 1;   // benign same-value races
    }
    __syncthreads();
    int i = base + t;
    int lab = -2;
    if (i < N_ANCH) {
        float amax = __uint_as_float((unsigned)(ws->akey[i] >> 32));
        lab = (amax < 0.3f) ? 0 : ((amax >= 0.7f || flg[t]) ? 1 : -1);
        ws->lab[i] = lab;
    }
    unsigned long long b1 = __ballot(lab == 1), b0 = __ballot(lab == 0);
    if (lane == 0) { wp[wid] = __popcll(b1); wn[wid] = __popcll(b0); }
    __syncthreads();
    if (t == 0) {
        ws->cnt_p[b] = wp[0] + wp[1] + wp[2] + wp[3];
        ws->cnt_n[b] = wn[0] + wn[1] + wn[2] + wn[3];
    }
}

// ---------------- K3: demote-first selection + local loss + last-block finalize ----------------
__global__ __launch_bounds__(256) void k_closs(const float* __restrict__ pred,
                                               const float* __restrict__ gtb,
                                               const int* __restrict__ gtl,
                                               WS* __restrict__ ws,
                                               float* __restrict__ out) {
    __shared__ int wps[4], wns[4];
    __shared__ float red[12];
    int b = blockIdx.x, t = threadIdx.x, lane = t & 63, wid = t >> 6;
    // redundant per-block totals + prefix (tiny, L2-hot)
    int npa = 0, nna = 0, pb = 0, nb = 0;
    for (int c = 0; c < N_CHUNK; ++c) {
        int cp = ws->cnt_p[c], cn = ws->cnt_n[c];
        if (c < b) { pb += cp; nb += cn; }
        npa += cp; nna += cn;
    }
    int excess_pos = (npa > 128) ? (npa - 128) : 0;
    int n_pos_f = npa - excess_pos;
    int n_neg_req = 256 - n_pos_f;
    int excess_neg = (nna > n_neg_req) ? (nna - n_neg_req) : 0;
    int n_neg_f = nna - excess_neg;

    int i = b * 256 + t;
    int lab = (i < N_ANCH) ? ws->lab[i] : -2;
    bool f1 = (lab == 1), f0 = (lab == 0);
    unsigned long long b1 = __ballot(f1), b0v = __ballot(f0);
    unsigned long long pm = (2ull << lane) - 1ull;   // inclusive mask
    int r1 = __popcll(b1 & pm), r0 = __popcll(b0v & pm);
    if (lane == 0) { wps[wid] = __popcll(b1); wns[wid] = __popcll(b0v); }
    __syncthreads();
    int p1 = 0, p0 = 0;
    for (int w = 0; w < wid; ++w) { p1 += wps[w]; p0 += wns[w]; }

    float acc_a = 0.f, acc_c = 0.f, acc_n = 0.f;
    if (f1 && (pb + p1 + r1) > excess_pos) {
        // surviving positive: full 85-term row
        unsigned am = ~(unsigned)(ws->akey[i]);
        float4 box = ((const float4*)gtb)[am];
        int cls = gtl[am] + 5;
        const float* pr = pred + i * N_OUTC;
        float d0 = pr[0] - box.x, d1 = pr[1] - box.y;
        float d2 = pr[2] - box.z, d3 = pr[3] - box.w;
        acc_a = d0*d0 + d1*d1 + d2*d2 + d3*d3 + bce(pr[4], 1.0f);
        for (int c = 5; c < N_OUTC; ++c)
            acc_c += bce(pr[c], (c == cls) ? 1.0f : 0.0f);
    }
    if (f0 && (nb + p0 + r0) > excess_neg) {
        acc_n = bce(pred[i * N_OUTC + 4], 0.0f);
    }
    for (int o = 32; o; o >>= 1) {
        acc_a += __shfl_down(acc_a, o);
        acc_c += __shfl_down(acc_c, o);
        acc_n += __shfl_down(acc_n, o);
    }
    if (lane == 0) { red[wid] = acc_a; red[4 + wid] = acc_c; red[8 + wid] = acc_n; }
    __syncthreads();
    if (t == 0) {
        float A = red[0] + red[1] + red[2] + red[3];
        float C = red[4] + red[5] + red[6] + red[7];
        float Nn = red[8] + red[9] + red[10] + red[11];
        atomicAdd(&ws->acc[0], A);
        atomicAdd(&ws->acc[1], C);
        atomicAdd(&ws->acc[2], Nn);
        __threadfence();
        unsigned old = atomicAdd(&ws->done, 1u);
        if (old == N_CHUNK - 1) {
            float Af = atomicAdd(&ws->acc[0], 0.0f);
            float Cf = atomicAdd(&ws->acc[1], 0.0f);
            float Nf = atomicAdd(&ws->acc[2], 0.0f);
            float np = fmaxf((float)n_pos_f, 1.0f);
            float nn = fmaxf((float)n_neg_f, 1.0f);
            out[PRED_ELEMS] = Af / np + Nf / nn + Cf / (np * 80.0f);
        }
    }
}

extern "C" void kernel_launch(void* const* d_in, const int* in_sizes, int n_in,
                              void* d_out, int out_size, void* d_ws, size_t ws_size,
                              hipStream_t stream) {
    const float* pred   = (const float*)d_in[0];
    const float* gtb    = (const float*)d_in[1];
    const int*   gtl    = (const int*)d_in[2];
    const float* priors = (const float*)d_in[3];
    float* out = (float*)d_out;
    WS* ws = (WS*)d_ws;

    hipMemsetAsync(d_ws, 0, sizeof(WS), stream);
    k_iou<<<dim3(NBLK_IOU), 256, 0, stream>>>(pred, gtb, priors, out, ws);
    k_label<<<dim3(N_CHUNK), 256, 0, stream>>>(ws);
    k_closs<<<dim3(N_CHUNK), 256, 0, stream>>>(pred, gtb, gtl, ws, out);
}

// Round 5
// 77.599 us; speedup vs baseline: 1.1360x; 1.1360x over previous
//
#include <hip/hip_runtime.h>
#include <math.h>

#define N_ANCH 10647
#define N_GT   2048
#define N_OUTC 85
#define PRED_ELEMS (N_ANCH * N_OUTC)   // 904995
#define PRED_V4    (PRED_ELEMS / 4)    // 226248 (3 tail floats)
#define N_CHUNK    42                  // ceil(10647/256)
#define NBLK_A     176                 // 11 bx * 16 by  (anchor side, ILP4)
#define NBLK_G     336                 // 4 bx * 84 by   (gt side, ILP2)
#define NBLK_IOU   (NBLK_A + NBLK_G)   // 512 = 2 per CU
#define CPY_PER_BLK ((PRED_V4 + NBLK_IOU - 1) / NBLK_IOU)   // 442

struct WS {
    unsigned long long akey[N_ANCH];   // packed (iou_bits<<32)|~gt_idx   (memset 0)
    unsigned long long gkey[N_GT];     // packed (iou_bits<<32)|~anchor_idx (memset 0)
    int lab[N_ANCH];                   // -1/0/1 labels (pre-demote)
    int cnt_p[N_CHUNK], cnt_n[N_CHUNK];
    float acc[3];                      // box+obj, cls, neg  (memset 0)
};

__device__ __forceinline__ float bce(float x, float t) {
    // matches: max(x,0) - x*t + log1p(exp(-|x|))
    return fmaxf(x, 0.0f) - x * t + log1pf(expf(-fabsf(x)));
}

__device__ __forceinline__ unsigned long long packkey(float iou, int idx) {
    return ((unsigned long long)__float_as_uint(iou) << 32) |
           (unsigned)(~(unsigned)idx);
}

__device__ __forceinline__ float iou_one(const float4& a, float aa,
                                         const float4& g, float ga) {
    float lx = fmaxf(a.x, g.x), ly = fmaxf(a.y, g.y);
    float rx = fminf(a.z, g.z), ry = fminf(a.w, g.w);
    float w  = fmaxf(rx - lx, 0.0f), h = fmaxf(ry - ly, 0.0f);
    float inter = w * h;
    return inter / ((aa + ga) - inter);   // IEEE div: bitwise == reference
}

// ---------------- K1: pred->out copy + fused IoU reductions ----------------
// blocks [0,176):   anchor side. bx=b%11 (1024 anchors, 4/thread), by=b/11 (16 x 128 GTs)
// blocks [176,512): gt side.     bx=b2%4 (512 GTs, 2/thread),      by=b2/4 (84 x 128 anchors)
__global__ __launch_bounds__(256) void k_iou(const float* __restrict__ pred,
                                             const float* __restrict__ gtb,
                                             const float* __restrict__ priors,
                                             float* __restrict__ out,
                                             WS* __restrict__ ws) {
    int b = blockIdx.x, t = threadIdx.x;
    // distributed pred -> out copy (small, overlaps with compute)
    for (int k = t; k < CPY_PER_BLK; k += 256) {
        int idx = b * CPY_PER_BLK + k;
        if (idx < PRED_V4)
            ((float4*)out)[idx] = ((const float4*)pred)[idx];
    }
    if (b == 0 && t == 0) {
        out[PRED_ELEMS - 3] = pred[PRED_ELEMS - 3];
        out[PRED_ELEMS - 2] = pred[PRED_ELEMS - 2];
        out[PRED_ELEMS - 1] = pred[PRED_ELEMS - 1];
    }

    __shared__ float4 sc[128];
    __shared__ float  sa[128];

    if (b < NBLK_A) {
        // ---- anchor side, 4 anchors per thread ----
        int bx = b % 11, by = b / 11;
        int jbase = by * 128;
        if (t < 128) {
            float4 v = ((const float4*)gtb)[jbase + t];
            float4 c = make_float4(v.x - v.z*0.5f, v.y - v.w*0.5f,
                                   v.x + v.z*0.5f, v.y + v.w*0.5f);
            sc[t] = c;
            sa[t] = (c.z - c.x) * (c.w - c.y);
        }
        float4 a[4]; float aa[4]; int iarr[4]; bool val[4];
#pragma unroll
        for (int u = 0; u < 4; ++u) {
            int i = bx * 1024 + u * 256 + t;
            iarr[u] = i; val[u] = (i < N_ANCH);
            a[u] = make_float4(0.f, 0.f, 0.f, 0.f); aa[u] = 0.f;
            if (val[u]) {
                float cx = priors[i*N_OUTC+0], cy = priors[i*N_OUTC+1];
                float w  = priors[i*N_OUTC+2], h  = priors[i*N_OUTC+3];
                a[u] = make_float4(cx - w*0.5f, cy - h*0.5f, cx + w*0.5f, cy + h*0.5f);
                aa[u] = (a[u].z - a[u].x) * (a[u].w - a[u].y);
            }
        }
        __syncthreads();
        float bi[4] = {-1.f, -1.f, -1.f, -1.f};
        int bj[4] = {0, 0, 0, 0};
#pragma unroll 2
        for (int jj = 0; jj < 128; ++jj) {
            float4 g = sc[jj]; float ga = sa[jj];
#pragma unroll
            for (int u = 0; u < 4; ++u) {
                float iou = iou_one(a[u], aa[u], g, ga);
                bool c = iou > bi[u];          // strict > : first index on ties
                bi[u] = c ? iou : bi[u];
                bj[u] = c ? jj : bj[u];
            }
        }
#pragma unroll
        for (int u = 0; u < 4; ++u)
            if (val[u]) atomicMax(&ws->akey[iarr[u]], packkey(bi[u], jbase + bj[u]));
    } else {
        // ---- gt side, 2 GTs per thread ----
        int b2 = b - NBLK_A;
        int bx = b2 % 4, by = b2 / 4;
        int ibase = by * 128;
        if (t < 128) {
            int i = ibase + t;
            float4 c = make_float4(0.f, 0.f, 0.f, 0.f);
            float ar = 0.f;
            if (i < N_ANCH) {
                float cx = priors[i*N_OUTC+0], cy = priors[i*N_OUTC+1];
                float w  = priors[i*N_OUTC+2], h  = priors[i*N_OUTC+3];
                c = make_float4(cx - w*0.5f, cy - h*0.5f, cx + w*0.5f, cy + h*0.5f);
                ar = (c.z - c.x) * (c.w - c.y);
            }
            // pads: iou = 0 at chunk-tail; strict > never picks them over an
            // earlier real anchor with iou >= 0.
            sc[t] = c; sa[t] = ar;
        }
        int j0 = bx * 512 + t, j1 = j0 + 256;
        float4 v = ((const float4*)gtb)[j0];
        float4 g0 = make_float4(v.x - v.z*0.5f, v.y - v.w*0.5f,
                                v.x + v.z*0.5f, v.y + v.w*0.5f);
        float ga0 = (g0.z - g0.x) * (g0.w - g0.y);
        v = ((const float4*)gtb)[j1];
        float4 g1 = make_float4(v.x - v.z*0.5f, v.y - v.w*0.5f,
                                v.x + v.z*0.5f, v.y + v.w*0.5f);
        float ga1 = (g1.z - g1.x) * (g1.w - g1.y);
        __syncthreads();
        float bi0 = -1.0f, bi1 = -1.0f;
        int bii0 = 0, bii1 = 0;
#pragma unroll 4
        for (int ii = 0; ii < 128; ++ii) {
            float4 ax = sc[ii]; float aax = sa[ii];
            float iou0 = iou_one(ax, aax, g0, ga0);
            float iou1 = iou_one(ax, aax, g1, ga1);
            bool c0 = iou0 > bi0;
            bi0 = c0 ? iou0 : bi0; bii0 = c0 ? ii : bii0;
            bool c1 = iou1 > bi1;
            bi1 = c1 ? iou1 : bi1; bii1 = c1 ? ii : bii1;
        }
        atomicMax(&ws->gkey[j0], packkey(bi0, ibase + bii0));
        atomicMax(&ws->gkey[j1], packkey(bi1, ibase + bii1));
    }
}

// ---------------- K2: per-chunk labels + counts (parallel) ----------------
__global__ __launch_bounds__(256) void k_label(WS* __restrict__ ws) {
    __shared__ int flg[256];
    __shared__ int wp[4], wn[4];
    int b = blockIdx.x, t = threadIdx.x, base = b * 256;
    int lane = t & 63, wid = t >> 6;
    flg[t] = 0;
    __syncthreads();
    for (int j = t; j < N_GT; j += 256) {
        int ai = (int)(~(unsigned)(ws->gkey[j]));
        int rel = ai - base;
        if ((unsigned)rel < 256u) flg[rel] = 1;   // benign same-value races
    }
    __syncthreads();
    int i = base + t;
    int lab = -2;
    if (i < N_ANCH) {
        float amax = __uint_as_float((unsigned)(ws->akey[i] >> 32));
        // note: amax<0.3 forces 0 even for gt-max anchors (reference order)
        lab = (amax < 0.3f) ? 0 : ((amax >= 0.7f || flg[t]) ? 1 : -1);
        ws->lab[i] = lab;
    }
    unsigned long long b1 = __ballot(lab == 1), b0 = __ballot(lab == 0);
    if (lane == 0) { wp[wid] = __popcll(b1); wn[wid] = __popcll(b0); }
    __syncthreads();
    if (t == 0) {
        ws->cnt_p[b] = wp[0] + wp[1] + wp[2] + wp[3];
        ws->cnt_n[b] = wn[0] + wn[1] + wn[2] + wn[3];
    }
}

// ---------------- K3: demote-first selection + column-parallel loss ----------------
__global__ __launch_bounds__(256) void k_closs(const float* __restrict__ pred,
                                               const float* __restrict__ gtb,
                                               const int* __restrict__ gtl,
                                               WS* __restrict__ ws) {
    __shared__ int wps[4], wns[4];
    __shared__ int    sPosI[256];
    __shared__ float4 sPosBox[256];
    __shared__ int    sPosCls[256];
    __shared__ int    sNegI[256];
    __shared__ float  red[12];
    int b = blockIdx.x, t = threadIdx.x, lane = t & 63, wid = t >> 6;

    // redundant per-block totals + prefix (fully unrolled scalar loads)
    int npa = 0, nna = 0, pb = 0, nb = 0;
#pragma unroll
    for (int c = 0; c < N_CHUNK; ++c) {
        int cp = ws->cnt_p[c], cn = ws->cnt_n[c];
        if (c < b) { pb += cp; nb += cn; }
        npa += cp; nna += cn;
    }
    int excess_pos = (npa > 128) ? (npa - 128) : 0;
    int n_pos_f = npa - excess_pos;
    int n_neg_req = 256 - n_pos_f;
    int excess_neg = (nna > n_neg_req) ? (nna - n_neg_req) : 0;

    int i = b * 256 + t;
    int lab = (i < N_ANCH) ? ws->lab[i] : -2;
    bool f1 = (lab == 1), f0 = (lab == 0);
    unsigned long long b1 = __ballot(f1), b0v = __ballot(f0);
    unsigned long long pm = (2ull << lane) - 1ull;   // inclusive mask
    int r1 = __popcll(b1 & pm), r0 = __popcll(b0v & pm);
    if (lane == 0) { wps[wid] = __popcll(b1); wns[wid] = __popcll(b0v); }
    __syncthreads();
    int p1 = 0, p0 = 0, cpB = 0, cnB = 0;
    for (int w = 0; w < 4; ++w) {
        int v1 = wps[w], v0 = wns[w];
        cpB += v1; cnB += v0;
        if (w < wid) { p1 += v1; p0 += v0; }
    }
    // local-rank survival thresholds (survivors are a suffix of local ranks)
    int thp = excess_pos - pb; thp = (thp < 0) ? 0 : thp;
    int thn = excess_neg - nb; thn = (thn < 0) ? 0 : thn;
    if (f1) {
        int L = p1 + r1;                 // 1-based local inclusive rank
        if (L > thp) {
            int slot = L - thp - 1;
            sPosI[slot] = i;
            unsigned am = ~(unsigned)(ws->akey[i]);
            sPosBox[slot] = ((const float4*)gtb)[am];
            sPosCls[slot] = gtl[am] + 5;
        }
    }
    if (f0) {
        int L = p0 + r0;
        if (L > thn) sNegI[L - thn - 1] = i;
    }
    __syncthreads();
    int nP = cpB - thp; nP = (nP < 0) ? 0 : nP;
    int nN = cnB - thn; nN = (nN < 0) ? 0 : nN;

    // column-parallel loss over block-local survivors (coalesced pred reads)
    float acc_a = 0.f, acc_c = 0.f, acc_n = 0.f;
    int nT = nP * N_OUTC;
    for (int u = t; u < nT; u += 256) {
        int pi = u / N_OUTC, col = u - pi * N_OUTC;
        float p = pred[sPosI[pi] * N_OUTC + col];
        if (col < 4) {
            float d = p - ((const float*)&sPosBox[pi])[col];
            acc_a += d * d;
        } else if (col == 4) {
            acc_a += bce(p, 1.0f);
        } else {
            acc_c += bce(p, (col == sPosCls[pi]) ? 1.0f : 0.0f);
        }
    }
    for (int u = t; u < nN; u += 256)
        acc_n += bce(pred[sNegI[u] * N_OUTC + 4], 0.0f);

    for (int o = 32; o; o >>= 1) {
        acc_a += __shfl_down(acc_a, o);
        acc_c += __shfl_down(acc_c, o);
        acc_n += __shfl_down(acc_n, o);
    }
    if (lane == 0) { red[wid] = acc_a; red[4 + wid] = acc_c; red[8 + wid] = acc_n; }
    __syncthreads();
    if (t == 0) {
        float A  = red[0] + red[1] + red[2]  + red[3];
        float C  = red[4] + red[5] + red[6]  + red[7];
        float Nn = red[8] + red[9] + red[10] + red[11];
        if (A  != 0.f) atomicAdd(&ws->acc[0], A);
        if (C  != 0.f) atomicAdd(&ws->acc[1], C);
        if (Nn != 0.f) atomicAdd(&ws->acc[2], Nn);
    }
}

// ---------------- K4: finalize scalar (also a last-dispatch canary) ----------------
__global__ __launch_bounds__(64) void k_final(WS* __restrict__ ws,
                                              float* __restrict__ out) {
    int t = threadIdx.x;
    int cp = (t < N_CHUNK) ? ws->cnt_p[t] : 0;
    int cn = (t < N_CHUNK) ? ws->cnt_n[t] : 0;
    for (int o = 32; o; o >>= 1) { cp += __shfl_down(cp, o); cn += __shfl_down(cn, o); }
    if (t == 0) {
        int npa = cp, nna = cn;
        int excess_pos = (npa > 128) ? (npa - 128) : 0;
        int n_pos_f = npa - excess_pos;
        int n_neg_req = 256 - n_pos_f;
        int excess_neg = (nna > n_neg_req) ? (nna - n_neg_req) : 0;
        int n_neg_f = nna - excess_neg;
        float np = fmaxf((float)n_pos_f, 1.0f);
        float nn = fmaxf((float)n_neg_f, 1.0f);
        out[PRED_ELEMS] = ws->acc[0] / np + ws->acc[2] / nn + ws->acc[1] / (np * 80.0f);
    }
}

extern "C" void kernel_launch(void* const* d_in, const int* in_sizes, int n_in,
                              void* d_out, int out_size, void* d_ws, size_t ws_size,
                              hipStream_t stream) {
    const float* pred   = (const float*)d_in[0];
    const float* gtb    = (const float*)d_in[1];
    const int*   gtl    = (const int*)d_in[2];
    const float* priors = (const float*)d_in[3];
    float* out = (float*)d_out;
    WS* ws = (WS*)d_ws;

    hipMemsetAsync(d_ws, 0, sizeof(WS), stream);
    k_iou<<<dim3(NBLK_IOU), 256, 0, stream>>>(pred, gtb, priors, out, ws);
    k_label<<<dim3(N_CHUNK), 256, 0, stream>>>(ws);
    k_closs<<<dim3(N_CHUNK), 256, 0, stream>>>(pred, gtb, gtl, ws);
    k_final<<<1, 64, 0, stream>>>(ws, out);
}

// Round 6
// 69.549 us; speedup vs baseline: 1.2675x; 1.1158x over previous
//
#include <hip/hip_runtime.h>
#include <math.h>

#define N_ANCH 10647
#define N_GT   2048
#define N_OUTC 85
#define PRED_ELEMS (N_ANCH * N_OUTC)   // 904995
#define PRED_V4    (PRED_ELEMS / 4)    // 226248 (3 tail floats)
#define N_CHUNK    42                  // ceil(10647/256)

// k_iou geometry: 64-entry LDS chunks, ILP-2, big grid for occupancy
#define ABX 21                         // anchor side: 21 x 512 anchors (2/thread)
#define ABY 32                         //              32 x 64-GT chunks
#define NBLK_A (ABX * ABY)             // 672
#define GBX 4                          // gt side: 4 x 512 GTs (2/thread)
#define GBY 167                        //          167 x 64-anchor chunks (pad tail)
#define NBLK_G (GBX * GBY)             // 668
#define NBLK_IOU (NBLK_A + NBLK_G)     // 1340
#define CPY_PER_BLK ((PRED_V4 + NBLK_IOU - 1) / NBLK_IOU)   // 169

struct WS {
    // ---- memset-zeroed region (keep contiguous at front) ----
    unsigned long long akey[N_ANCH];   // packed (iou_bits<<32)|~gt_idx
    unsigned long long gkey[N_GT];     // packed (iou_bits<<32)|~anchor_idx
    float acc[3];                      // box+obj, cls, neg
    float pad_;
    // ---- write-before-read region ----
    int lab[N_ANCH];                   // -1/0/1 labels (pre-demote)
    int cnt_p[N_CHUNK], cnt_n[N_CHUNK];
};
#define MEMSET_BYTES (N_ANCH * 8 + N_GT * 8 + 16)

__device__ __forceinline__ float bce(float x, float t) {
    // matches: max(x,0) - x*t + log1p(exp(-|x|))
    return fmaxf(x, 0.0f) - x * t + log1pf(expf(-fabsf(x)));
}

__device__ __forceinline__ unsigned long long packkey(float iou, int idx) {
    return ((unsigned long long)__float_as_uint(iou) << 32) |
           (unsigned)(~(unsigned)idx);
}

// ---------------- K1: pred->out copy + fused IoU reductions ----------------
// Argmax state per candidate-slot: (I=inter, S=areaA+areaB, idx).
// iou = I/(S-I); compare via cross-mult (monotone, denominators > 0).
// Winner's iou computed once with IEEE div -> bitwise == reference value.
__global__ __launch_bounds__(256) void k_iou(const float* __restrict__ pred,
                                             const float* __restrict__ gtb,
                                             const float* __restrict__ priors,
                                             float* __restrict__ out,
                                             WS* __restrict__ ws) {
    int b = blockIdx.x, t = threadIdx.x;
    // distributed pred -> out copy (1 float4 per thread)
    if (t < CPY_PER_BLK) {
        int idx = b * CPY_PER_BLK + t;
        if (idx < PRED_V4)
            ((float4*)out)[idx] = ((const float4*)pred)[idx];
    }
    if (b == 0 && t == 0) {
        out[PRED_ELEMS - 3] = pred[PRED_ELEMS - 3];
        out[PRED_ELEMS - 2] = pred[PRED_ELEMS - 2];
        out[PRED_ELEMS - 1] = pred[PRED_ELEMS - 1];
    }

    __shared__ float4 sc[64];
    __shared__ float  sa[64];

    if (b < NBLK_A) {
        // ---- anchor side: 2 anchors/thread vs 64 GTs in LDS ----
        int bx = b % ABX, by = b / ABX;
        int jbase = by * 64;
        if (t < 64) {
            float4 v = ((const float4*)gtb)[jbase + t];
            float4 c = make_float4(v.x - v.z*0.5f, v.y - v.w*0.5f,
                                   v.x + v.z*0.5f, v.y + v.w*0.5f);
            sc[t] = c;
            sa[t] = (c.z - c.x) * (c.w - c.y);
        }
        int i0 = bx * 512 + t, i1 = i0 + 256;
        bool v0 = (i0 < N_ANCH), v1 = (i1 < N_ANCH);
        float4 a0 = make_float4(0.f,0.f,0.f,0.f), a1 = a0;
        float aa0 = 0.f, aa1 = 0.f;
        if (v0) {
            float cx = priors[i0*N_OUTC+0], cy = priors[i0*N_OUTC+1];
            float w  = priors[i0*N_OUTC+2], h  = priors[i0*N_OUTC+3];
            a0 = make_float4(cx - w*0.5f, cy - h*0.5f, cx + w*0.5f, cy + h*0.5f);
            aa0 = (a0.z - a0.x) * (a0.w - a0.y);
        }
        if (v1) {
            float cx = priors[i1*N_OUTC+0], cy = priors[i1*N_OUTC+1];
            float w  = priors[i1*N_OUTC+2], h  = priors[i1*N_OUTC+3];
            a1 = make_float4(cx - w*0.5f, cy - h*0.5f, cx + w*0.5f, cy + h*0.5f);
            aa1 = (a1.z - a1.x) * (a1.w - a1.y);
        }
        __syncthreads();
        float I0 = -1.f, S0 = 1.f, I1 = -1.f, S1 = 1.f;
        int bj0 = 0, bj1 = 0;
#pragma unroll 4
        for (int jj = 0; jj < 64; ++jj) {
            float4 g = sc[jj]; float ga = sa[jj];
            float lx = fmaxf(a0.x, g.x), ly = fmaxf(a0.y, g.y);
            float rx = fminf(a0.z, g.z), ry = fminf(a0.w, g.w);
            float In = fmaxf(rx - lx, 0.f) * fmaxf(ry - ly, 0.f);
            float Sn = aa0 + ga;
            bool c = In * S0 > I0 * Sn;      // strict: first index on ties
            I0 = c ? In : I0; S0 = c ? Sn : S0; bj0 = c ? jj : bj0;
            lx = fmaxf(a1.x, g.x); ly = fmaxf(a1.y, g.y);
            rx = fminf(a1.z, g.z); ry = fminf(a1.w, g.w);
            In = fmaxf(rx - lx, 0.f) * fmaxf(ry - ly, 0.f);
            Sn = aa1 + ga;
            c = In * S1 > I1 * Sn;
            I1 = c ? In : I1; S1 = c ? Sn : S1; bj1 = c ? jj : bj1;
        }
        if (v0) atomicMax(&ws->akey[i0], packkey(I0 / (S0 - I0), jbase + bj0));
        if (v1) atomicMax(&ws->akey[i1], packkey(I1 / (S1 - I1), jbase + bj1));
    } else {
        // ---- gt side: 2 GTs/thread vs 64 anchors in LDS ----
        int b2 = b - NBLK_A;
        int bx = b2 % GBX, by = b2 / GBX;
        int ibase = by * 64;
        if (t < 64) {
            int i = ibase + t;
            float4 c = make_float4(0.f, 0.f, 0.f, 0.f);
            float ar = 0.f;
            if (i < N_ANCH) {
                float cx = priors[i*N_OUTC+0], cy = priors[i*N_OUTC+1];
                float w  = priors[i*N_OUTC+2], h  = priors[i*N_OUTC+3];
                c = make_float4(cx - w*0.5f, cy - h*0.5f, cx + w*0.5f, cy + h*0.5f);
                ar = (c.z - c.x) * (c.w - c.y);
            }
            // pads: I=0 -> cross-mult 0 > I_b*S is false for I_b>=0, and the
            // first candidate of every chunk is real -> pads never win.
            sc[t] = c; sa[t] = ar;
        }
        int j0 = bx * 512 + t, j1 = j0 + 256;
        float4 v = ((const float4*)gtb)[j0];
        float4 g0 = make_float4(v.x - v.z*0.5f, v.y - v.w*0.5f,
                                v.x + v.z*0.5f, v.y + v.w*0.5f);
        float ga0 = (g0.z - g0.x) * (g0.w - g0.y);
        v = ((const float4*)gtb)[j1];
        float4 g1 = make_float4(v.x - v.z*0.5f, v.y - v.w*0.5f,
                                v.x + v.z*0.5f, v.y + v.w*0.5f);
        float ga1 = (g1.z - g1.x) * (g1.w - g1.y);
        __syncthreads();
        float I0 = -1.f, S0 = 1.f, I1 = -1.f, S1 = 1.f;
        int bi0 = 0, bi1 = 0;
#pragma unroll 4
        for (int ii = 0; ii < 64; ++ii) {
            float4 a = sc[ii]; float aa = sa[ii];
            float lx = fmaxf(a.x, g0.x), ly = fmaxf(a.y, g0.y);
            float rx = fminf(a.z, g0.z), ry = fminf(a.w, g0.w);
            float In = fmaxf(rx - lx, 0.f) * fmaxf(ry - ly, 0.f);
            float Sn = aa + ga0;
            bool c = In * S0 > I0 * Sn;
            I0 = c ? In : I0; S0 = c ? Sn : S0; bi0 = c ? ii : bi0;
            lx = fmaxf(a.x, g1.x); ly = fmaxf(a.y, g1.y);
            rx = fminf(a.z, g1.z); ry = fminf(a.w, g1.w);
            In = fmaxf(rx - lx, 0.f) * fmaxf(ry - ly, 0.f);
            Sn = aa + ga1;
            c = In * S1 > I1 * Sn;
            I1 = c ? In : I1; S1 = c ? Sn : S1; bi1 = c ? ii : bi1;
        }
        atomicMax(&ws->gkey[j0], packkey(I0 / (S0 - I0), ibase + bi0));
        atomicMax(&ws->gkey[j1], packkey(I1 / (S1 - I1), ibase + bi1));
    }
}

// ---------------- K2: per-chunk labels + counts (parallel) ----------------
__global__ __launch_bounds__(256) void k_label(WS* __restrict__ ws) {
    __shared__ int flg[256];
    __shared__ int wp[4], wn[4];
    int b = blockIdx.x, t = threadIdx.x, base = b * 256;
    int lane = t & 63, wid = t >> 6;
    flg[t] = 0;
    __syncthreads();
    for (int j = t; j < N_GT; j += 256) {
        int ai = (int)(~(unsigned)(ws->gkey[j]));
        int rel = ai - base;
        if ((unsigned)rel < 256u) flg[rel] = 1;   // benign same-value races
    }
    __syncthreads();
    int i = base + t;
    int lab = -2;
    if (i < N_ANCH) {
        float amax = __uint_as_float((unsigned)(ws->akey[i] >> 32));
        lab = (amax < 0.3f) ? 0 : ((amax >= 0.7f || flg[t]) ? 1 : -1);
        ws->lab[i] = lab;
    }
    unsigned long long b1 = __ballot(lab == 1), b0 = __ballot(lab == 0);
    if (lane == 0) { wp[wid] = __popcll(b1); wn[wid] = __popcll(b0); }
    __syncthreads();
    if (t == 0) {
        ws->cnt_p[b] = wp[0] + wp[1] + wp[2] + wp[3];
        ws->cnt_n[b] = wn[0] + wn[1] + wn[2] + wn[3];
    }
}

// ---------------- K3: demote-first selection + column-parallel loss ----------------
__global__ __launch_bounds__(256) void k_closs(const float* __restrict__ pred,
                                               const float* __restrict__ gtb,
                                               const int* __restrict__ gtl,
                                               WS* __restrict__ ws) {
    __shared__ int wps[4], wns[4];
    __shared__ int    sPosI[256];
    __shared__ float4 sPosBox[256];
    __shared__ int    sPosCls[256];
    __shared__ int    sNegI[256];
    __shared__ float  red[12];
    int b = blockIdx.x, t = threadIdx.x, lane = t & 63, wid = t >> 6;

    int npa = 0, nna = 0, pb = 0, nb = 0;
#pragma unroll
    for (int c = 0; c < N_CHUNK; ++c) {
        int cp = ws->cnt_p[c], cn = ws->cnt_n[c];
        if (c < b) { pb += cp; nb += cn; }
        npa += cp; nna += cn;
    }
    int excess_pos = (npa > 128) ? (npa - 128) : 0;
    int n_pos_f = npa - excess_pos;
    int n_neg_req = 256 - n_pos_f;
    int excess_neg = (nna > n_neg_req) ? (nna - n_neg_req) : 0;

    int i = b * 256 + t;
    int lab = (i < N_ANCH) ? ws->lab[i] : -2;
    bool f1 = (lab == 1), f0 = (lab == 0);
    unsigned long long b1 = __ballot(f1), b0v = __ballot(f0);
    unsigned long long pm = (2ull << lane) - 1ull;   // inclusive mask
    int r1 = __popcll(b1 & pm), r0 = __popcll(b0v & pm);
    if (lane == 0) { wps[wid] = __popcll(b1); wns[wid] = __popcll(b0v); }
    __syncthreads();
    int p1 = 0, p0 = 0, cpB = 0, cnB = 0;
    for (int w = 0; w < 4; ++w) {
        int v1 = wps[w], v0 = wns[w];
        cpB += v1; cnB += v0;
        if (w < wid) { p1 += v1; p0 += v0; }
    }
    int thp = excess_pos - pb; thp = (thp < 0) ? 0 : thp;
    int thn = excess_neg - nb; thn = (thn < 0) ? 0 : thn;
    if (f1) {
        int L = p1 + r1;
        if (L > thp) {
            int slot = L - thp - 1;
            sPosI[slot] = i;
            unsigned am = ~(unsigned)(ws->akey[i]);
            sPosBox[slot] = ((const float4*)gtb)[am];
            sPosCls[slot] = gtl[am] + 5;
        }
    }
    if (f0) {
        int L = p0 + r0;
        if (L > thn) sNegI[L - thn - 1] = i;
    }
    __syncthreads();
    int nP = cpB - thp; nP = (nP < 0) ? 0 : nP;
    int nN = cnB - thn; nN = (nN < 0) ? 0 : nN;

    float acc_a = 0.f, acc_c = 0.f, acc_n = 0.f;
    int nT = nP * N_OUTC;
    for (int u = t; u < nT; u += 256) {
        int pi = u / N_OUTC, col = u - pi * N_OUTC;
        float p = pred[sPosI[pi] * N_OUTC + col];
        if (col < 4) {
            float d = p - ((const float*)&sPosBox[pi])[col];
            acc_a += d * d;
        } else if (col == 4) {
            acc_a += bce(p, 1.0f);
        } else {
            acc_c += bce(p, (col == sPosCls[pi]) ? 1.0f : 0.0f);
        }
    }
    for (int u = t; u < nN; u += 256)
        acc_n += bce(pred[sNegI[u] * N_OUTC + 4], 0.0f);

    for (int o = 32; o; o >>= 1) {
        acc_a += __shfl_down(acc_a, o);
        acc_c += __shfl_down(acc_c, o);
        acc_n += __shfl_down(acc_n, o);
    }
    if (lane == 0) { red[wid] = acc_a; red[4 + wid] = acc_c; red[8 + wid] = acc_n; }
    __syncthreads();
    if (t == 0) {
        float A  = red[0] + red[1] + red[2]  + red[3];
        float C  = red[4] + red[5] + red[6]  + red[7];
        float Nn = red[8] + red[9] + red[10] + red[11];
        if (A  != 0.f) atomicAdd(&ws->acc[0], A);
        if (C  != 0.f) atomicAdd(&ws->acc[1], C);
        if (Nn != 0.f) atomicAdd(&ws->acc[2], Nn);
    }
}

// ---------------- K4: finalize scalar ----------------
__global__ __launch_bounds__(64) void k_final(WS* __restrict__ ws,
                                              float* __restrict__ out) {
    int t = threadIdx.x;
    int cp = (t < N_CHUNK) ? ws->cnt_p[t] : 0;
    int cn = (t < N_CHUNK) ? ws->cnt_n[t] : 0;
    for (int o = 32; o; o >>= 1) { cp += __shfl_down(cp, o); cn += __shfl_down(cn, o); }
    if (t == 0) {
        int npa = cp, nna = cn;
        int excess_pos = (npa > 128) ? (npa - 128) : 0;
        int n_pos_f = npa - excess_pos;
        int n_neg_req = 256 - n_pos_f;
        int excess_neg = (nna > n_neg_req) ? (nna - n_neg_req) : 0;
        int n_neg_f = nna - excess_neg;
        float np = fmaxf((float)n_pos_f, 1.0f);
        float nn = fmaxf((float)n_neg_f, 1.0f);
        out[PRED_ELEMS] = ws->acc[0] / np + ws->acc[2] / nn + ws->acc[1] / (np * 80.0f);
    }
}

extern "C" void kernel_launch(void* const* d_in, const int* in_sizes, int n_in,
                              void* d_out, int out_size, void* d_ws, size_t ws_size,
                              hipStream_t stream) {
    const float* pred   = (const float*)d_in[0];
    const float* gtb    = (const float*)d_in[1];
    const int*   gtl    = (const int*)d_in[2];
    const float* priors = (const float*)d_in[3];
    float* out = (float*)d_out;
    WS* ws = (WS*)d_ws;

    hipMemsetAsync(d_ws, 0, MEMSET_BYTES, stream);
    k_iou<<<dim3(NBLK_IOU), 256, 0, stream>>>(pred, gtb, priors, out, ws);
    k_label<<<dim3(N_CHUNK), 256, 0, stream>>>(ws);
    k_closs<<<dim3(N_CHUNK), 256, 0, stream>>>(pred, gtb, gtl, ws);
    k_final<<<1, 64, 0, stream>>>(ws, out);
}